// Round 12
// baseline (41.255 us; speedup 1.0000x reference)
//
#include <hip/hip_runtime.h>
#include <hip/hip_bf16.h>
#include <cmath>

#define NTOK 4096

typedef float        f32x16 __attribute__((ext_vector_type(16)));
typedef short        s16x8  __attribute__((ext_vector_type(8)));
typedef unsigned int u32x4  __attribute__((ext_vector_type(4)));

__device__ __forceinline__ unsigned short f2bf(float f) {
    __hip_bfloat16 h = __float2bfloat16(f);
    return *reinterpret_cast<unsigned short*>(&h);
}
__device__ __forceinline__ float bf2f(unsigned short u) {
    __hip_bfloat16 h = *reinterpret_cast<__hip_bfloat16*>(&u);
    return __bfloat162float(h);
}
// packed f32x2 -> bf16x2 via HIP intrinsic (lowers to v_cvt_pk_bf16_f32)
__device__ __forceinline__ unsigned pk2(float a, float b) {
    __hip_bfloat162 h = __float22bfloat162_rn(make_float2(a, b));
    return *reinterpret_cast<unsigned*>(&h);
}

// ---------------------------------------------------------------------------
// Kernel 1: QKV projection, 10-part split, PART-MAJOR grid (proven R9/R10).
// Grid 2560 = part*256 + vg; XCD = vg % 8 fixed across parts -> x slice
// L2-resident.  p=0 -> q (log2e-scaled, hi/lo), p=1 -> k (hi/lo),
// p>=2 -> V rows, j-tiled + slot-permuted (sigma = swap b2<->b3).
// ---------------------------------------------------------------------------
__global__ __launch_bounds__(64)
void qkv_kernel(const float* __restrict__ x,
                const float* __restrict__ Wq, const float* __restrict__ bq,
                const float* __restrict__ Wk, const float* __restrict__ bk,
                const float* __restrict__ Wv, const float* __restrict__ bv,
                unsigned short* __restrict__ qt2, unsigned short* __restrict__ kt2,
                unsigned short* __restrict__ vt)
{
    __shared__ float wlds[8 * 64];
    __shared__ float blds[8];
    const int t    = threadIdx.x;
    const int part = blockIdx.x >> 8;    // 0..9  (chunk index)
    const int vg   = blockIdx.x & 255;

    float4* w4 = (float4*)wlds;
    #pragma unroll
    for (int rr = 0; rr < 2; rr++) {
        const int idx  = rr * 64 + t;          // 0..127 float4 slots
        const int row  = idx >> 4;             // local 0..7
        const int col4 = idx & 15;
        const int g    = part * 8 + row;
        const float* src = (g < 8)  ? (Wq + g * 64)
                         : (g < 16) ? (Wk + (g - 8) * 64)
                                    : (Wv + (g - 16) * 64);
        w4[idx] = ((const float4*)src)[col4];
    }
    if (t < 8) {
        const int g = part * 8 + t;
        blds[t] = (g < 8) ? bq[g] : (g < 16) ? bk[g - 8] : bv[g - 16];
    }
    __syncthreads();

    const int gid = vg * 64 + t;
    const int b = gid >> 12;
    const int i = gid & (NTOK - 1);
    const float* xb = x + ((size_t)b * 64) * NTOK + i;
    float xv[64];
    #pragma unroll
    for (int c = 0; c < 64; c++) xv[c] = xb[(size_t)c * NTOK];

    float a[8];
    #pragma unroll
    for (int o = 0; o < 8; o++) a[o] = blds[o];
    #pragma unroll
    for (int c4 = 0; c4 < 16; c4++) {
        #pragma unroll
        for (int o = 0; o < 8; o++) {
            float4 wv4 = ((const float4*)wlds)[o * 16 + c4];
            a[o] += wv4.x * xv[c4*4+0] + wv4.y * xv[c4*4+1]
                  + wv4.z * xv[c4*4+2] + wv4.w * xv[c4*4+3];
        }
    }

    const size_t row = (size_t)b * NTOK + i;
    if (part < 2) {
        if (part == 0) {
            const float LOG2E = 1.4426950408889634f;
            #pragma unroll
            for (int o = 0; o < 8; o++) a[o] *= LOG2E;
        }
        unsigned short hu[8], lu[8];
        #pragma unroll
        for (int o = 0; o < 8; o++) {
            hu[o] = f2bf(a[o]);
            lu[o] = f2bf(a[o] - bf2f(hu[o]));
        }
        unsigned short* dst = (part == 0 ? qt2 : kt2) + row * 16;
        ((u32x4*)dst)[0] = *(const u32x4*)hu;
        ((u32x4*)dst)[1] = *(const u32x4*)lu;
    } else {
        const int jl   = i & 15;
        const int slot = (jl & 3) | ((jl & 4) << 1) | ((jl & 8) >> 1);  // swap b2<->b3
        const int cbase = (part - 2) * 8;
        unsigned short* vdst =
            vt + ((size_t)b * 256 + (i >> 4)) * 1024 + (size_t)cbase * 16 + slot;
        #pragma unroll
        for (int o = 0; o < 8; o++)
            vdst[o * 16] = f2bf(a[o]);
    }
}

// ---------------------------------------------------------------------------
// Kernel 2: fused flash attention, full-MFMA, no-max exp2 softmax,
// STAGGERED PIPELINE (T15): QK^T of chunk it+1 is issued BEFORE the
// exp/pack/PV of chunk it, so QK-MFMA latency and the VALU softmax overlap
// instead of serializing.  sc/sn double score state (static regs).
// K prefetch depth-2 (consumed at iter start), V depth-1.  cvt_pk packing
// via __float22bfloat162_rn.  Zero cross-lane in the j-loop (j-permuted
// V^T).  8 waves/block, additive 3-round LDS merge, fused epilogue.
// ---------------------------------------------------------------------------
__global__ __launch_bounds__(512)
void attn_kernel(const unsigned short* __restrict__ qt2,
                 const unsigned short* __restrict__ kt2,
                 const unsigned short* __restrict__ vt,
                 const float* __restrict__ x,
                 const float* __restrict__ gamma,
                 float* __restrict__ out)
{
    __shared__ float slds[4][64][32];   // merge slots [c][q], 32 KB
    __shared__ float sldl[4][32];       // l per slot

    const int t    = threadIdx.x;
    const int l    = t & 63;
    const int wv   = t >> 6;
    const int lo31 = l & 31;
    const int h    = l >> 5;
    const int w     = blockIdx.x;
    const int b     = w >> 7;
    const int qbase = (w & 127) << 5;
    const int j0    = wv << 9;          // 512 j per wave

    // Q B-frags: B1 = [q_hi|q_hi], B2 = [q_lo|0]
    const unsigned short* qrow = qt2 + ((size_t)b * NTOK + qbase + lo31) * 16;
    s16x8 qB1 = *(const s16x8*)qrow;
    s16x8 qB2;
    if (h == 0) qB2 = *(const s16x8*)(qrow + 8);
    else        { u32x4 z = {0,0,0,0}; qB2 = __builtin_bit_cast(s16x8, z); }

    const unsigned short* kb  = kt2 + (size_t)b * NTOK * 16 + (size_t)h * 8;
    // V^T tiled: vt[b][t16][c][slot]; lane base for accA (c=lo31) / accB (+32)
    const unsigned short* vbA = vt + (size_t)b * NTOK * 64 + (size_t)lo31 * 16 + 8 * h;
    const unsigned short* vbB = vbA + 512;

    f32x16 accA, accB, zf;
    #pragma unroll
    for (int r = 0; r < 16; r++) { accA[r] = 0.f; accB[r] = 0.f; zf[r] = 0.f; }
    float lsum = 0.f;

    s16x8 K[2], V00[2], V01[2], V10[2], V11[2];

    #define LOADK(s_, a_)                                                     \
        K[s_] = *(const s16x8*)(kb + (size_t)(j0 + ((a_) << 5) + lo31) * 16)
    #define LOADV(s_, a_) do {                                                \
        V00[s_] = *(const s16x8*)(vbA + (size_t)((j0 >> 4) + ((a_) << 1)) * 1024);     \
        V01[s_] = *(const s16x8*)(vbA + (size_t)((j0 >> 4) + ((a_) << 1) + 1) * 1024); \
        V10[s_] = *(const s16x8*)(vbB + (size_t)((j0 >> 4) + ((a_) << 1)) * 1024);     \
        V11[s_] = *(const s16x8*)(vbB + (size_t)((j0 >> 4) + ((a_) << 1) + 1) * 1024); \
    } while (0)

    // prologue: chunk-0 loads, chunk-0 scores, chunk-1 K
    LOADK(0, 0);
    LOADV(0, 0);
    f32x16 sc;
    sc = __builtin_amdgcn_mfma_f32_32x32x16_bf16(K[0], qB1, zf, 0, 0, 0);
    sc = __builtin_amdgcn_mfma_f32_32x32x16_bf16(K[0], qB2, sc, 0, 0, 0);
    LOADK(1, 1);

    #pragma unroll
    for (int it = 0; it < 16; ++it) {
        const int nxK = it + 2;
        LOADK(it & 1, (nxK < 16) ? nxK : 0);     // K for chunk it+2

        // QK^T for chunk it+1 (issues on MFMA pipe; VALU below overlaps)
        const int ks = (it + 1) & 1;
        f32x16 sn;
        sn = __builtin_amdgcn_mfma_f32_32x32x16_bf16(K[ks], qB1, zf, 0, 0, 0);
        sn = __builtin_amdgcn_mfma_f32_32x32x16_bf16(K[ks], qB2, sn, 0, 0, 0);

        const int nxV = it + 1;
        LOADV((it + 1) & 1, (nxV < 16) ? nxV : 0);   // V for chunk it+1

        // ---- softmax finish of chunk it: p = exp2(sc) raw ----
        #pragma unroll
        for (int r = 0; r < 16; r++) sc[r] = __builtin_amdgcn_exp2f(sc[r]);

        lsum += ((sc[0]+sc[1])+(sc[2]+sc[3])) + ((sc[4]+sc[5])+(sc[6]+sc[7]))
              + ((sc[8]+sc[9])+(sc[10]+sc[11])) + ((sc[12]+sc[13])+(sc[14]+sc[15]));

        // ---- P^T -> B-frags: direct repack via v_cvt_pk_bf16_f32 ----
        u32x4 wa, wc;
        wa.x = pk2(sc[0], sc[1]);   wa.y = pk2(sc[2], sc[3]);
        wa.z = pk2(sc[4], sc[5]);   wa.w = pk2(sc[6], sc[7]);
        wc.x = pk2(sc[8], sc[9]);   wc.y = pk2(sc[10], sc[11]);
        wc.z = pk2(sc[12], sc[13]); wc.w = pk2(sc[14], sc[15]);
        s16x8 pf0 = __builtin_bit_cast(s16x8, wa);
        s16x8 pf1 = __builtin_bit_cast(s16x8, wc);

        // ---- PV for chunk it ----
        const int vs = it & 1;
        __builtin_amdgcn_s_setprio(1);
        accA = __builtin_amdgcn_mfma_f32_32x32x16_bf16(V00[vs], pf0, accA, 0, 0, 0);
        accA = __builtin_amdgcn_mfma_f32_32x32x16_bf16(V01[vs], pf1, accA, 0, 0, 0);
        accB = __builtin_amdgcn_mfma_f32_32x32x16_bf16(V10[vs], pf0, accB, 0, 0, 0);
        accB = __builtin_amdgcn_mfma_f32_32x32x16_bf16(V11[vs], pf1, accB, 0, 0, 0);
        __builtin_amdgcn_s_setprio(0);

        sc = sn;
    }

    // combine halves of l once
    lsum += __shfl_xor(lsum, 32);

    // ---- 3-round ADDITIVE LDS tree merge of 8 wave-partials ----
    #define WR_SLOT(sidx) do {                                                \
        const int s_ = (sidx);                                                \
        _Pragma("unroll")                                                     \
        for (int r = 0; r < 16; r++) {                                        \
            const int c_ = (r & 3) + 8 * (r >> 2) + 4 * h;                    \
            slds[s_][c_][lo31]      = accA[r];                                \
            slds[s_][c_ + 32][lo31] = accB[r];                                \
        }                                                                     \
        if (h == 0) sldl[s_][lo31] = lsum;                                    \
    } while (0)

    #define MRG_SLOT(sidx) do {                                               \
        const int s_ = (sidx);                                                \
        _Pragma("unroll")                                                     \
        for (int r = 0; r < 16; r++) {                                        \
            const int c_ = (r & 3) + 8 * (r >> 2) + 4 * h;                    \
            accA[r] += slds[s_][c_][lo31];                                    \
            accB[r] += slds[s_][c_ + 32][lo31];                               \
        }                                                                     \
        lsum += sldl[s_][lo31];                                               \
    } while (0)

    if (wv >= 4) WR_SLOT(wv - 4);
    __syncthreads();
    if (wv < 4) MRG_SLOT(wv);
    __syncthreads();
    if (wv == 2 || wv == 3) WR_SLOT(wv - 2);
    __syncthreads();
    if (wv < 2) MRG_SLOT(wv);
    __syncthreads();
    if (wv == 1) WR_SLOT(0);
    __syncthreads();
    if (wv == 0) { MRG_SLOT(0); WR_SLOT(0); }
    __syncthreads();

    // ---- fused epilogue: out = gamma*acc/L + x, all 512 threads ----
    const int c  = t >> 3;
    const int q4 = (t & 7) << 2;
    const float g = gamma[0];
    const float4 a4 = *(const float4*)&slds[0][c][q4];
    const float g0 = g / sldl[0][q4 + 0];
    const float g1 = g / sldl[0][q4 + 1];
    const float g2 = g / sldl[0][q4 + 2];
    const float g3 = g / sldl[0][q4 + 3];
    const size_t off = (((size_t)b * 64 + c) << 12) + qbase + q4;
    const float4 xv4 = *(const float4*)(x + off);
    float4 o;
    o.x = a4.x * g0 + xv4.x;
    o.y = a4.y * g1 + xv4.y;
    o.z = a4.z * g2 + xv4.z;
    o.w = a4.w * g3 + xv4.w;
    *(float4*)(out + off) = o;
}

// ---------------------------------------------------------------------------
extern "C" void kernel_launch(void* const* d_in, const int* in_sizes, int n_in,
                              void* d_out, int out_size, void* d_ws, size_t ws_size,
                              hipStream_t stream) {
    const float* x     = (const float*)d_in[0];
    const float* Wq    = (const float*)d_in[1];
    const float* bq    = (const float*)d_in[2];
    const float* Wk    = (const float*)d_in[3];
    const float* bk    = (const float*)d_in[4];
    const float* Wv    = (const float*)d_in[5];
    const float* bv    = (const float*)d_in[6];
    const float* gamma = (const float*)d_in[7];
    float* out = (float*)d_out;

    unsigned short* qt2 = (unsigned short*)d_ws;            // 4*4096*16 bf16
    unsigned short* kt2 = qt2 + (size_t)4 * NTOK * 16;      // 4*4096*16 bf16
    unsigned short* vt  = kt2 + (size_t)4 * NTOK * 16;      // 4*4096*64 bf16 (tiled+permuted)

    qkv_kernel<<<2560, 64, 0, stream>>>(x, Wq, bq, Wk, bk, Wv, bv, qt2, kt2, vt);
    attn_kernel<<<512, 512, 0, stream>>>(qt2, kt2, vt, x, gamma, out);
}